// Round 6
// baseline (1287.482 us; speedup 1.0000x reference)
//
#include <hip/hip_runtime.h>
#include <hip/hip_bf16.h>

// LSTM2: B=1024, T=1024, H=64. R6: R5's MFMA design + duplicate-MFMA /
// split-cell latency hiding.
// 64 blocks (16 batches each) x 8 waves (512 thr). Waves (w, half):
// both halves compute the SAME MFMA tiles for unit-group w (MFMA pipe is
// ~15% busy and co-issues with VALU across waves), but the cell/activation
// work (the dominant VALU cost) is split: half 0 -> acc regs r=0,1,
// half 1 -> r=2,3. 2 waves/SIMD now interleave, hiding ds_read (~120cyc),
// MFMA-chain and exp-chain latency that R5 (1 wave/SIMD) ate raw.
// Same 2-barrier hazard structure as R5 (audited; h1 halves disjoint,
// headp per-half slots).
//   A: A[m=lane&15][k=(lane>>4)*8+j]   B: B[k=(lane>>4)*8+j][n=lane&15]
//   C/D: row=(lane>>4)*4+reg, col=lane&15   (learn_hip m89/m91/m120)

typedef _Float16 f16x8 __attribute__((ext_vector_type(8)));
typedef _Float16 f16x2 __attribute__((ext_vector_type(2)));
typedef float    f32x4 __attribute__((ext_vector_type(4)));

namespace {
constexpr int Bb = 1024;
constexpr int Tt = 1024;
constexpr int HSTR = 72;   // f16 stride per batch row of h (2-way max = free)
constexpr int XSTR = 1025; // f32 stride per batch row of x (conflict-free)

__device__ __forceinline__ float sigm(float x) {
    float e = __builtin_amdgcn_exp2f(-1.4426950408889634f * x);
    return __builtin_amdgcn_rcpf(1.0f + e);
}
__device__ __forceinline__ float tanh_f(float x) {
    float e = __builtin_amdgcn_exp2f(-2.8853900817779268f * x);
    return __builtin_amdgcn_rcpf(1.0f + e) * 2.0f - 1.0f;
}
// Dtype sniff (proven R2-R5): fp32 data at even bf16 indices has random
// exponent fields; genuine bf16 weights ~N(0,0.125) are ~always in-range.
__device__ __forceinline__ bool detect_f32(const void* w) {
    const unsigned short* p = (const unsigned short*)w;
    int sane = 0;
    for (int i = 0; i < 64; ++i) {
        int e = (p[2 * i] >> 7) & 0xFF;
        if (e >= 107 && e <= 129) ++sane;
    }
    return sane < 32;
}
__device__ __forceinline__ float ld(const void* p, int i, bool f32) {
    return f32 ? ((const float*)p)[i]
               : __bfloat162float(((const __hip_bfloat16*)p)[i]);
}
__device__ __forceinline__ void st(void* p, int i, float v, bool f32) {
    if (f32) ((float*)p)[i] = v;
    else     ((__hip_bfloat16*)p)[i] = __float2bfloat16(v);
}
} // namespace

__global__ __launch_bounds__(512, 1) void lstm2_kernel(
    const void* __restrict__ x,      // [B, T]
    const void* __restrict__ w_ih1,  // [256, 1]
    const void* __restrict__ w_hh1,  // [256, 64]
    const void* __restrict__ b_ih1,  // [256]
    const void* __restrict__ b_hh1,  // [256]
    const void* __restrict__ w_ih2,  // [256, 64]
    const void* __restrict__ w_hh2,  // [256, 64]
    const void* __restrict__ b_ih2,  // [256]
    const void* __restrict__ b_hh2,  // [256]
    const void* __restrict__ w_lin,  // [1, 64]
    const void* __restrict__ b_lin,  // [1]
    void* __restrict__ out)          // [B, T]
{
    const int tid  = threadIdx.x;
    const int lane = tid & 63;
    const int w    = (tid >> 6) & 3;  // unit group 16w..16w+15
    const int hf   = tid >> 8;        // cell-half: 0 -> r=0,1 ; 1 -> r=2,3
    const int m    = lane & 15;       // batch within block (B-col / D-col)
    const int quad = lane >> 4;
    const int bb   = blockIdx.x * 16;

    const bool f32 = detect_f32(w_hh1);

    __shared__ float    xs[16 * XSTR];      // staged x, fp32
    __shared__ _Float16 h1l[16 * HSTR];     // h1 in B-layout [batch][unit]
    __shared__ _Float16 h2l[16 * HSTR];     // h2 in B-layout
    __shared__ float    headp[128];         // head partials [hf][w][batch]

    // ---- stage x (one-time, coalesced) + zero h buffers ----
    for (int i = tid; i < 16 * 1024; i += 512)
        xs[(i >> 10) * XSTR + (i & 1023)] = ld(x, (bb + (i >> 10)) * Tt + (i & 1023), f32);
    for (int i = tid; i < 16 * HSTR; i += 512) { h1l[i] = (_Float16)0; h2l[i] = (_Float16)0; }

    // ---- one-time: A-fragments of W_hh1 / W_ih2 / W_hh2 (96 VGPRs) ----
    // frag element j: W[64*q + 16*w + m][32*s + quad*8 + j]
    f16x8 wf1[4][2], wf2[4][2], wf3[4][2];
    if (f32) {
        const float* W1 = (const float*)w_hh1;
        const float* W2 = (const float*)w_ih2;
        const float* W3 = (const float*)w_hh2;
#pragma unroll
        for (int q = 0; q < 4; ++q) {
            const int row = 64 * q + 16 * w + m;
#pragma unroll
            for (int s = 0; s < 2; ++s) {
                const int base = row * 64 + 32 * s + quad * 8;
#pragma unroll
                for (int j = 0; j < 8; ++j) {
                    wf1[q][s][j] = (_Float16)W1[base + j];
                    wf2[q][s][j] = (_Float16)W2[base + j];
                    wf3[q][s][j] = (_Float16)W3[base + j];
                }
            }
        }
    } else {
        const __hip_bfloat16* W1 = (const __hip_bfloat16*)w_hh1;
        const __hip_bfloat16* W2 = (const __hip_bfloat16*)w_ih2;
        const __hip_bfloat16* W3 = (const __hip_bfloat16*)w_hh2;
#pragma unroll
        for (int q = 0; q < 4; ++q) {
            const int row = 64 * q + 16 * w + m;
#pragma unroll
            for (int s = 0; s < 2; ++s) {
                const int base = row * 64 + 32 * s + quad * 8;
#pragma unroll
                for (int j = 0; j < 8; ++j) {
                    wf1[q][s][j] = (_Float16)__bfloat162float(W1[base + j]);
                    wf2[q][s][j] = (_Float16)__bfloat162float(W2[base + j]);
                    wf3[q][s][j] = (_Float16)__bfloat162float(W3[base + j]);
                }
            }
        }
    }
    // ---- per-(tile,reg) scalars: D rows = 64*q + 16*w + quad*4 + r ----
    float b1v[4][4], b2v[4][4], wxv[4][4], wl2[2];
#pragma unroll
    for (int q = 0; q < 4; ++q)
#pragma unroll
        for (int r = 0; r < 4; ++r) {
            const int row = 64 * q + 16 * w + quad * 4 + r;
            b1v[q][r] = ld(b_ih1, row, f32) + ld(b_hh1, row, f32);
            b2v[q][r] = ld(b_ih2, row, f32) + ld(b_hh2, row, f32);
            wxv[q][r] = ld(w_ih1, row, f32);
        }
#pragma unroll
    for (int j = 0; j < 2; ++j)
        wl2[j] = ld(w_lin, 16 * w + quad * 4 + 2 * hf + j, f32);
    const float blin = ld(b_lin, 0, f32);

    f16x8 bh1[2] = {};            // h1 B-frags (h1_{t-1}; zero at t=0)
    float c1[2] = {0.0f, 0.0f};   // cell state for r = 2*hf + j, batch m
    float c2[2] = {0.0f, 0.0f};
    __syncthreads();

    const int xrow = m * XSTR;
    float xt = xs[xrow];

    for (int t = 0; t < Tt; ++t) {
        // prefetch h2_{t-1} B-frags (written pre-B3 of t-1; B1 separates WAR)
        f16x8 bh2[2];
        bh2[0] = *(const f16x8*)(h2l + m * HSTR + 0  + quad * 8);
        bh2[1] = *(const f16x8*)(h2l + m * HSTR + 32 + quad * 8);
        const float xtn = xs[xrow + ((t + 1 < Tt) ? t + 1 : t)];

        // ---- layer 1: gates = W1.h1_{t-1} + x*wx + b1 (both halves) ----
        f32x4 a1[4];
#pragma unroll
        for (int q = 0; q < 4; ++q)
#pragma unroll
            for (int r = 0; r < 4; ++r) a1[q][r] = fmaf(xt, wxv[q][r], b1v[q][r]);
#pragma unroll
        for (int q = 0; q < 4; ++q) {
            a1[q] = __builtin_amdgcn_mfma_f32_16x16x32_f16(wf1[q][0], bh1[0], a1[q], 0, 0, 0);
            a1[q] = __builtin_amdgcn_mfma_f32_16x16x32_f16(wf1[q][1], bh1[1], a1[q], 0, 0, 0);
        }
        // cell 1, split: this half handles r = 2*hf, 2*hf+1 (unit 16w+quad*4+r)
        f16x2 h1o;
#pragma unroll
        for (int j = 0; j < 2; ++j) {
            const int r = 2 * hf + j;
            float ig = sigm(a1[0][r]), fg = sigm(a1[1][r]);
            float gg = tanh_f(a1[2][r]), og = sigm(a1[3][r]);
            c1[j] = fmaf(fg, c1[j], ig * gg);
            h1o[j] = (_Float16)(og * tanh_f(c1[j]));
        }
        *(f16x2*)(h1l + m * HSTR + 16 * w + quad * 4 + 2 * hf) = h1o;
        __syncthreads();                                   // B1: h1_t ready

        // fresh h1_t B-frags (also reused by L1 of t+1 -- same vector)
        bh1[0] = *(const f16x8*)(h1l + m * HSTR + 0  + quad * 8);
        bh1[1] = *(const f16x8*)(h1l + m * HSTR + 32 + quad * 8);

        // ---- layer 2: gates = W2.h1_t + W3.h2_{t-1} + b2 (both halves) ----
        f32x4 a2[4];
#pragma unroll
        for (int q = 0; q < 4; ++q)
#pragma unroll
            for (int r = 0; r < 4; ++r) a2[q][r] = b2v[q][r];
#pragma unroll
        for (int q = 0; q < 4; ++q) {
            a2[q] = __builtin_amdgcn_mfma_f32_16x16x32_f16(wf2[q][0], bh1[0], a2[q], 0, 0, 0);
            a2[q] = __builtin_amdgcn_mfma_f32_16x16x32_f16(wf2[q][1], bh1[1], a2[q], 0, 0, 0);
            a2[q] = __builtin_amdgcn_mfma_f32_16x16x32_f16(wf3[q][0], bh2[0], a2[q], 0, 0, 0);
            a2[q] = __builtin_amdgcn_mfma_f32_16x16x32_f16(wf3[q][1], bh2[1], a2[q], 0, 0, 0);
        }
        // cell 2 (split) + head partial over this half's 2 units
        f16x2 h2o;
        float p = 0.0f;
#pragma unroll
        for (int j = 0; j < 2; ++j) {
            const int r = 2 * hf + j;
            float ig = sigm(a2[0][r]), fg = sigm(a2[1][r]);
            float gg = tanh_f(a2[2][r]), og = sigm(a2[3][r]);
            c2[j] = fmaf(fg, c2[j], ig * gg);
            float h = og * tanh_f(c2[j]);
            h2o[j] = (_Float16)h;
            p = fmaf(h, wl2[j], p);
        }
        *(f16x2*)(h2l + m * HSTR + 16 * w + quad * 4 + 2 * hf) = h2o;
        p += __shfl_xor(p, 16);
        p += __shfl_xor(p, 32);           // sum over quads (8 units this half)
        if (quad == 0) headp[hf * 64 + w * 16 + m] = p;
        __syncthreads();                                   // B3: h2_t + partials

        if (tid < 16) {
            float s = blin;
#pragma unroll
            for (int k = 0; k < 8; ++k) s += headp[k * 16 + tid];
            st(out, (bb + tid) * Tt + t, s, f32);
        }
        xt = xtn;
    }
}

extern "C" void kernel_launch(void* const* d_in, const int* in_sizes, int n_in,
                              void* d_out, int out_size, void* d_ws, size_t ws_size,
                              hipStream_t stream)
{
    (void)in_sizes; (void)n_in; (void)out_size; (void)d_ws; (void)ws_size;
    lstm2_kernel<<<dim3(Bb / 16), dim3(512), 0, stream>>>(
        d_in[0], d_in[1], d_in[2], d_in[3], d_in[4], d_in[5],
        d_in[6], d_in[7], d_in[8], d_in[9], d_in[10], d_out);
}

// Round 7
// 1167.880 us; speedup vs baseline: 1.1024x; 1.1024x over previous
//
#include <hip/hip_runtime.h>
#include <hip/hip_bf16.h>

// LSTM2: B=1024, T=1024, H=64. R7: all-256-CU MFMA design.
// 256 blocks (4 batches each) x 4 waves. MFMA tiles keep M=16 units, N=16
// batch cols but only 4 cols are real (MFMA is ~15% util on active CUs --
// wasting cols to engage 4x more CUs is the right trade; cell/activation
// VALU, the real bottleneck, is per (unit,batch) and now spreads 4x wider).
//
// Pipeline (2 barriers/step): since L1(t+1)=W1.h1_t uses the SAME h1_t
// fragments as L2(t), one merged MFMA phase computes both:
//   Phase A (cell): cell1(t) [pre1] ; cell2(t-1) [pre2] + head + out(t-1)
//   Phase B (mfma): a2 = W2.h1_t + W3.h2_{t-1} + b2  -> pre2
//                   a1 = W1.h1_t + x_{t+1}*wx + b1   -> pre1
// Preacts redistribute via LDS: ds_write_b128 of each f32x4 acc (4 rows =
// 4 consecutive units) into pre[gate][batch][68] (pad 68 -> 2-way max);
// cell phase: 256 threads, thread = (batch=tid>>6, unit=tid&63), 1 eval per
// layer per thread (transcendental work per lane drops 4x vs R5).
// Layouts (learn_hip m89/m91/m120):
//   A: A[m=lane&15][k=(lane>>4)*8+j]  B: B[k=(lane>>4)*8+j][n=lane&15]
//   C/D: row=(lane>>4)*4+reg, col=lane&15

typedef _Float16 f16x8 __attribute__((ext_vector_type(8)));
typedef float    f32x4 __attribute__((ext_vector_type(4)));

namespace {
constexpr int Bb = 1024;
constexpr int Tt = 1024;
constexpr int NBat = 4;    // batches per block
constexpr int HSTR = 72;   // f16 stride per batch row of h
constexpr int XSTR = 1025; // f32 stride per batch row of x
constexpr int PSTR = 68;   // f32 stride per (gate,batch) row of preacts

__device__ __forceinline__ float sigm(float x) {
    float e = __builtin_amdgcn_exp2f(-1.4426950408889634f * x);
    return __builtin_amdgcn_rcpf(1.0f + e);
}
__device__ __forceinline__ float tanh_f(float x) {
    float e = __builtin_amdgcn_exp2f(-2.8853900817779268f * x);
    return __builtin_amdgcn_rcpf(1.0f + e) * 2.0f - 1.0f;
}
// Dtype sniff (proven R2-R6).
__device__ __forceinline__ bool detect_f32(const void* w) {
    const unsigned short* p = (const unsigned short*)w;
    int sane = 0;
    for (int i = 0; i < 64; ++i) {
        int e = (p[2 * i] >> 7) & 0xFF;
        if (e >= 107 && e <= 129) ++sane;
    }
    return sane < 32;
}
__device__ __forceinline__ float ld(const void* p, int i, bool f32) {
    return f32 ? ((const float*)p)[i]
               : __bfloat162float(((const __hip_bfloat16*)p)[i]);
}
__device__ __forceinline__ void st(void* p, int i, float v, bool f32) {
    if (f32) ((float*)p)[i] = v;
    else     ((__hip_bfloat16*)p)[i] = __float2bfloat16(v);
}
} // namespace

__global__ __launch_bounds__(256, 1) void lstm2_kernel(
    const void* __restrict__ x,      // [B, T]
    const void* __restrict__ w_ih1,  // [256, 1]
    const void* __restrict__ w_hh1,  // [256, 64]
    const void* __restrict__ b_ih1,  // [256]
    const void* __restrict__ b_hh1,  // [256]
    const void* __restrict__ w_ih2,  // [256, 64]
    const void* __restrict__ w_hh2,  // [256, 64]
    const void* __restrict__ b_ih2,  // [256]
    const void* __restrict__ b_hh2,  // [256]
    const void* __restrict__ w_lin,  // [1, 64]
    const void* __restrict__ b_lin,  // [1]
    void* __restrict__ out)          // [B, T]
{
    const int tid  = threadIdx.x;
    const int lane = tid & 63;
    const int w    = tid >> 6;       // wave -> unit group 16w..16w+15
    const int m    = lane & 15;      // D/B column (batch; valid m<4)
    const int quad = lane >> 4;
    const int bb   = blockIdx.x * NBat;

    const bool f32 = detect_f32(w_hh1);

    __shared__ float    xs[NBat * XSTR];    // staged x, fp32
    __shared__ _Float16 h1l[16 * HSTR];     // h1 B-layout [batch16][unit] (rows>=4 stay 0)
    __shared__ _Float16 h2l[16 * HSTR];     // h2 B-layout
    __shared__ float    pre1[4 * NBat * PSTR];  // L1 preacts [gate][batch][unit]
    __shared__ float    pre2[4 * NBat * PSTR];  // L2 preacts

    // ---- stage x (coalesced) + zero h buffers ----
    for (int i = tid; i < NBat * 1024; i += 256)
        xs[(i >> 10) * XSTR + (i & 1023)] = ld(x, (bb + (i >> 10)) * Tt + (i & 1023), f32);
    for (int i = tid; i < 16 * HSTR; i += 256) { h1l[i] = (_Float16)0; h2l[i] = (_Float16)0; }

    // ---- one-time: A-fragments (96 VGPRs): elem j = W[64q+16w+m][32s+quad*8+j]
    f16x8 wf1[4][2], wf2[4][2], wf3[4][2];
    if (f32) {
        const float* W1 = (const float*)w_hh1;
        const float* W2 = (const float*)w_ih2;
        const float* W3 = (const float*)w_hh2;
#pragma unroll
        for (int q = 0; q < 4; ++q) {
            const int row = 64 * q + 16 * w + m;
#pragma unroll
            for (int s = 0; s < 2; ++s) {
                const int base = row * 64 + 32 * s + quad * 8;
#pragma unroll
                for (int j = 0; j < 8; ++j) {
                    wf1[q][s][j] = (_Float16)W1[base + j];
                    wf2[q][s][j] = (_Float16)W2[base + j];
                    wf3[q][s][j] = (_Float16)W3[base + j];
                }
            }
        }
    } else {
        const __hip_bfloat16* W1 = (const __hip_bfloat16*)w_hh1;
        const __hip_bfloat16* W2 = (const __hip_bfloat16*)w_ih2;
        const __hip_bfloat16* W3 = (const __hip_bfloat16*)w_hh2;
#pragma unroll
        for (int q = 0; q < 4; ++q) {
            const int row = 64 * q + 16 * w + m;
#pragma unroll
            for (int s = 0; s < 2; ++s) {
                const int base = row * 64 + 32 * s + quad * 8;
#pragma unroll
                for (int j = 0; j < 8; ++j) {
                    wf1[q][s][j] = (_Float16)__bfloat162float(W1[base + j]);
                    wf2[q][s][j] = (_Float16)__bfloat162float(W2[base + j]);
                    wf3[q][s][j] = (_Float16)__bfloat162float(W3[base + j]);
                }
            }
        }
    }
    // per-(tile q, reg r) bias/wx vectors; D row = 64q + 16w + quad*4 + r
    f32x4 b1v[4], b2v[4], wxv[4];
#pragma unroll
    for (int q = 0; q < 4; ++q)
#pragma unroll
        for (int r = 0; r < 4; ++r) {
            const int row = 64 * q + 16 * w + quad * 4 + r;
            b1v[q][r] = ld(b_ih1, row, f32) + ld(b_hh1, row, f32);
            b2v[q][r] = ld(b_ih2, row, f32) + ld(b_hh2, row, f32);
            wxv[q][r] = ld(w_ih1, row, f32);
        }
    // cell-thread constants: thread = (batch cb, unit cu)
    const int cb = tid >> 6, cu = tid & 63;
    const float wl_u = ld(w_lin, cu, f32);
    const float blin = ld(b_lin, 0, f32);
    float c1 = 0.0f, c2 = 0.0f;
    __syncthreads();   // xs/h ready

    // ---- prologue: pre1(0) = x_0*wx + b1 (h1_{-1}=0, no MFMA) ----
    if (m < NBat) {
        const float x0 = xs[m * XSTR];
#pragma unroll
        for (int q = 0; q < 4; ++q) {
            f32x4 v;
#pragma unroll
            for (int r = 0; r < 4; ++r) v[r] = fmaf(x0, wxv[q][r], b1v[q][r]);
            *(f32x4*)&pre1[(q * NBat + m) * PSTR + 16 * w + quad * 4] = v;
        }
    }
    __syncthreads();

    for (int t = 0; t <= Tt; ++t) {
        // ---- Phase A: cells (1 eval per layer per thread) ----
        if (t < Tt) {
            float gi = pre1[(0 * NBat + cb) * PSTR + cu];
            float gf = pre1[(1 * NBat + cb) * PSTR + cu];
            float gz = pre1[(2 * NBat + cb) * PSTR + cu];
            float go = pre1[(3 * NBat + cb) * PSTR + cu];
            float ig = sigm(gi), fg = sigm(gf), gg = tanh_f(gz), og = sigm(go);
            c1 = fmaf(fg, c1, ig * gg);
            h1l[cb * HSTR + cu] = (_Float16)(og * tanh_f(c1));
        }
        if (t > 0) {
            float gi = pre2[(0 * NBat + cb) * PSTR + cu];
            float gf = pre2[(1 * NBat + cb) * PSTR + cu];
            float gz = pre2[(2 * NBat + cb) * PSTR + cu];
            float go = pre2[(3 * NBat + cb) * PSTR + cu];
            float ig = sigm(gi), fg = sigm(gf), gg = tanh_f(gz), og = sigm(go);
            c2 = fmaf(fg, c2, ig * gg);
            float h = og * tanh_f(c2);
            h2l[cb * HSTR + cu] = (_Float16)h;
            float p = h * wl_u;                  // wave == batch -> pure shuffle
#pragma unroll
            for (int off = 32; off > 0; off >>= 1) p += __shfl_xor(p, off, 64);
            if (cu == 0) st(out, (bb + cb) * Tt + (t - 1), p + blin, f32);
        }
        if (t == Tt) break;
        __syncthreads();                         // B1: h1_t, h2_{t-1} ready

        // ---- Phase B: merged MFMA (L2(t) and L1(t+1) share h1_t frags) ----
        const f16x8 bh1a = *(const f16x8*)(h1l + m * HSTR + quad * 8);
        const f16x8 bh1b = *(const f16x8*)(h1l + m * HSTR + 32 + quad * 8);
        const f16x8 bh2a = *(const f16x8*)(h2l + m * HSTR + quad * 8);
        const f16x8 bh2b = *(const f16x8*)(h2l + m * HSTR + 32 + quad * 8);
        const float xtn  = xs[(m & 3) * XSTR + ((t + 1 < Tt) ? t + 1 : t)];
#pragma unroll
        for (int q = 0; q < 4; ++q) {
            f32x4 a2 = __builtin_amdgcn_mfma_f32_16x16x32_f16(wf2[q][0], bh1a, b2v[q], 0, 0, 0);
            a2 = __builtin_amdgcn_mfma_f32_16x16x32_f16(wf2[q][1], bh1b, a2, 0, 0, 0);
            a2 = __builtin_amdgcn_mfma_f32_16x16x32_f16(wf3[q][0], bh2a, a2, 0, 0, 0);
            a2 = __builtin_amdgcn_mfma_f32_16x16x32_f16(wf3[q][1], bh2b, a2, 0, 0, 0);
            f32x4 a1;
#pragma unroll
            for (int r = 0; r < 4; ++r) a1[r] = fmaf(xtn, wxv[q][r], b1v[q][r]);
            a1 = __builtin_amdgcn_mfma_f32_16x16x32_f16(wf1[q][0], bh1a, a1, 0, 0, 0);
            a1 = __builtin_amdgcn_mfma_f32_16x16x32_f16(wf1[q][1], bh1b, a1, 0, 0, 0);
            if (m < NBat) {   // f32x4 spans 4 consecutive units -> b128, no repack
                *(f32x4*)&pre2[(q * NBat + m) * PSTR + 16 * w + quad * 4] = a2;
                *(f32x4*)&pre1[(q * NBat + m) * PSTR + 16 * w + quad * 4] = a1;
            }
        }
        __syncthreads();                         // B2: preacts ready
    }
}

extern "C" void kernel_launch(void* const* d_in, const int* in_sizes, int n_in,
                              void* d_out, int out_size, void* d_ws, size_t ws_size,
                              hipStream_t stream)
{
    (void)in_sizes; (void)n_in; (void)out_size; (void)d_ws; (void)ws_size;
    lstm2_kernel<<<dim3(Bb / NBat), dim3(256), 0, stream>>>(
        d_in[0], d_in[1], d_in[2], d_in[3], d_in[4], d_in[5],
        d_in[6], d_in[7], d_in[8], d_in[9], d_in[10], d_out);
}

// Round 8
// 1161.548 us; speedup vs baseline: 1.1084x; 1.0055x over previous
//
#include <hip/hip_runtime.h>
#include <hip/hip_bf16.h>

// LSTM2: B=1024, T=1024, H=64. R8: latency-interleaved MFMA design.
// Diagnosis R5-R7: ~2550 cyc/step invariant, both pipes idle -> per-step
// critical path (barrier -> ds_read -> transcendental chain -> barrier ->
// ds_read -> MFMA chain) fully exposed at 1 block/CU.
// Fix: 512 blocks x 2 batches -> 2 independent blocks/CU interleave their
// critical paths; plus cell1/cell2 now run on DIFFERENT waves (wave =
// (layer,batch), 1 eval/thread) halving Phase A's chain.
//
// Pipeline per block (2 barriers/step), carried from R7:
//   Phase A (cell): lw=0 waves: cell1(t) <- pre1 ; lw=1 waves: cell2(t-1)
//                   <- pre2 + head + out(t-1)
//   Phase B (mfma): pre2 = W2.h1_t + W3.h2_{t-1} + b2
//                   pre1 = W1.h1_t + x_{t+1}*wx + b1   (shared h1_t frags)
// Layouts (learn_hip m89/m91/m120):
//   A: A[m=lane&15][k=(lane>>4)*8+j]  B: B[k=(lane>>4)*8+j][n=lane&15]
//   C/D: row=(lane>>4)*4+reg, col=lane&15

typedef _Float16 f16x8 __attribute__((ext_vector_type(8)));
typedef float    f32x4 __attribute__((ext_vector_type(4)));

namespace {
constexpr int Bb = 1024;
constexpr int Tt = 1024;
constexpr int NBat = 2;    // batches per block
constexpr int HSTR = 72;   // f16 stride per batch row of h
constexpr int XSTR = 1025; // f32 stride per batch row of x
constexpr int PSTR = 68;   // f32 stride per (gate,batch) row of preacts

__device__ __forceinline__ float sigm(float x) {
    float e = __builtin_amdgcn_exp2f(-1.4426950408889634f * x);
    return __builtin_amdgcn_rcpf(1.0f + e);
}
__device__ __forceinline__ float tanh_f(float x) {
    float e = __builtin_amdgcn_exp2f(-2.8853900817779268f * x);
    return __builtin_amdgcn_rcpf(1.0f + e) * 2.0f - 1.0f;
}
// Dtype sniff (proven R2-R7).
__device__ __forceinline__ bool detect_f32(const void* w) {
    const unsigned short* p = (const unsigned short*)w;
    int sane = 0;
    for (int i = 0; i < 64; ++i) {
        int e = (p[2 * i] >> 7) & 0xFF;
        if (e >= 107 && e <= 129) ++sane;
    }
    return sane < 32;
}
__device__ __forceinline__ float ld(const void* p, int i, bool f32) {
    return f32 ? ((const float*)p)[i]
               : __bfloat162float(((const __hip_bfloat16*)p)[i]);
}
__device__ __forceinline__ void st(void* p, int i, float v, bool f32) {
    if (f32) ((float*)p)[i] = v;
    else     ((__hip_bfloat16*)p)[i] = __float2bfloat16(v);
}
} // namespace

__global__ __launch_bounds__(256, 2) void lstm2_kernel(
    const void* __restrict__ x,      // [B, T]
    const void* __restrict__ w_ih1,  // [256, 1]
    const void* __restrict__ w_hh1,  // [256, 64]
    const void* __restrict__ b_ih1,  // [256]
    const void* __restrict__ b_hh1,  // [256]
    const void* __restrict__ w_ih2,  // [256, 64]
    const void* __restrict__ w_hh2,  // [256, 64]
    const void* __restrict__ b_ih2,  // [256]
    const void* __restrict__ b_hh2,  // [256]
    const void* __restrict__ w_lin,  // [1, 64]
    const void* __restrict__ b_lin,  // [1]
    void* __restrict__ out)          // [B, T]
{
    const int tid  = threadIdx.x;
    const int lane = tid & 63;
    const int w    = tid >> 6;       // MFMA phase: wave -> unit group 16w..16w+15
    const int m    = lane & 15;      // D/B column (batch; valid m<NBat)
    const int quad = lane >> 4;
    const int bb   = blockIdx.x * NBat;

    const bool f32 = detect_f32(w_hh1);

    __shared__ float    xs[NBat * XSTR];    // staged x, fp32
    __shared__ _Float16 h1l[16 * HSTR];     // h1 B-layout [batch16][unit] (rows>=NBat stay 0)
    __shared__ _Float16 h2l[16 * HSTR];     // h2 B-layout
    __shared__ float    pre1[4 * NBat * PSTR];  // L1 preacts [gate][batch][unit]
    __shared__ float    pre2[4 * NBat * PSTR];  // L2 preacts

    // ---- stage x (coalesced) + zero h buffers ----
    for (int i = tid; i < NBat * 1024; i += 256)
        xs[(i >> 10) * XSTR + (i & 1023)] = ld(x, (bb + (i >> 10)) * Tt + (i & 1023), f32);
    for (int i = tid; i < 16 * HSTR; i += 256) { h1l[i] = (_Float16)0; h2l[i] = (_Float16)0; }

    // ---- one-time: A-fragments (96 VGPRs): elem j = W[64q+16w+m][32s+quad*8+j]
    f16x8 wf1[4][2], wf2[4][2], wf3[4][2];
    if (f32) {
        const float* W1 = (const float*)w_hh1;
        const float* W2 = (const float*)w_ih2;
        const float* W3 = (const float*)w_hh2;
#pragma unroll
        for (int q = 0; q < 4; ++q) {
            const int row = 64 * q + 16 * w + m;
#pragma unroll
            for (int s = 0; s < 2; ++s) {
                const int base = row * 64 + 32 * s + quad * 8;
#pragma unroll
                for (int j = 0; j < 8; ++j) {
                    wf1[q][s][j] = (_Float16)W1[base + j];
                    wf2[q][s][j] = (_Float16)W2[base + j];
                    wf3[q][s][j] = (_Float16)W3[base + j];
                }
            }
        }
    } else {
        const __hip_bfloat16* W1 = (const __hip_bfloat16*)w_hh1;
        const __hip_bfloat16* W2 = (const __hip_bfloat16*)w_ih2;
        const __hip_bfloat16* W3 = (const __hip_bfloat16*)w_hh2;
#pragma unroll
        for (int q = 0; q < 4; ++q) {
            const int row = 64 * q + 16 * w + m;
#pragma unroll
            for (int s = 0; s < 2; ++s) {
                const int base = row * 64 + 32 * s + quad * 8;
#pragma unroll
                for (int j = 0; j < 8; ++j) {
                    wf1[q][s][j] = (_Float16)__bfloat162float(W1[base + j]);
                    wf2[q][s][j] = (_Float16)__bfloat162float(W2[base + j]);
                    wf3[q][s][j] = (_Float16)__bfloat162float(W3[base + j]);
                }
            }
        }
    }
    // per-(tile q, reg r) bias/wx vectors; D row = 64q + 16w + quad*4 + r
    f32x4 b1v[4], b2v[4], wxv[4];
#pragma unroll
    for (int q = 0; q < 4; ++q)
#pragma unroll
        for (int r = 0; r < 4; ++r) {
            const int row = 64 * q + 16 * w + quad * 4 + r;
            b1v[q][r] = ld(b_ih1, row, f32) + ld(b_hh1, row, f32);
            b2v[q][r] = ld(b_ih2, row, f32) + ld(b_hh2, row, f32);
            wxv[q][r] = ld(w_ih1, row, f32);
        }
    // cell-thread mapping: wave = (layer lw, batch cb); thread = 1 cell eval
    const int lw = tid >> 7;          // 0: layer-1 cell, 1: layer-2 cell
    const int cb = (tid >> 6) & 1;    // batch within block
    const int cu = tid & 63;          // unit
    const float wl_u = ld(w_lin, cu, f32);
    const float blin = ld(b_lin, 0, f32);
    float cst = 0.0f;                 // c1 (lw=0) or c2 (lw=1) for (cb, cu)
    __syncthreads();   // xs/h ready

    // ---- prologue: pre1(0) = x_0*wx + b1 (h1_{-1}=0, no MFMA) ----
    if (m < NBat) {
        const float x0 = xs[m * XSTR];
#pragma unroll
        for (int q = 0; q < 4; ++q) {
            f32x4 v;
#pragma unroll
            for (int r = 0; r < 4; ++r) v[r] = fmaf(x0, wxv[q][r], b1v[q][r]);
            *(f32x4*)&pre1[(q * NBat + m) * PSTR + 16 * w + quad * 4] = v;
        }
    }
    __syncthreads();

    for (int t = 0; t <= Tt; ++t) {
        // ---- Phase A: cells, layers on separate waves (1 eval/thread) ----
        if (lw == 0) {
            if (t < Tt) {
                float gi = pre1[(0 * NBat + cb) * PSTR + cu];
                float gf = pre1[(1 * NBat + cb) * PSTR + cu];
                float gz = pre1[(2 * NBat + cb) * PSTR + cu];
                float go = pre1[(3 * NBat + cb) * PSTR + cu];
                float ig = sigm(gi), fg = sigm(gf), gg = tanh_f(gz), og = sigm(go);
                cst = fmaf(fg, cst, ig * gg);
                h1l[cb * HSTR + cu] = (_Float16)(og * tanh_f(cst));
            }
        } else {
            if (t > 0) {
                float gi = pre2[(0 * NBat + cb) * PSTR + cu];
                float gf = pre2[(1 * NBat + cb) * PSTR + cu];
                float gz = pre2[(2 * NBat + cb) * PSTR + cu];
                float go = pre2[(3 * NBat + cb) * PSTR + cu];
                float ig = sigm(gi), fg = sigm(gf), gg = tanh_f(gz), og = sigm(go);
                cst = fmaf(fg, cst, ig * gg);
                float h = og * tanh_f(cst);
                h2l[cb * HSTR + cu] = (_Float16)h;
                float p = h * wl_u;              // wave = (L2, batch) -> shuffle
#pragma unroll
                for (int off = 32; off > 0; off >>= 1) p += __shfl_xor(p, off, 64);
                if (cu == 0) st(out, (bb + cb) * Tt + (t - 1), p + blin, f32);
            }
        }
        if (t == Tt) break;
        __syncthreads();                         // B1: h1_t, h2_{t-1} ready

        // ---- Phase B: merged MFMA (L2(t) and L1(t+1) share h1_t frags) ----
        const f16x8 bh1a = *(const f16x8*)(h1l + m * HSTR + quad * 8);
        const f16x8 bh1b = *(const f16x8*)(h1l + m * HSTR + 32 + quad * 8);
        const f16x8 bh2a = *(const f16x8*)(h2l + m * HSTR + quad * 8);
        const f16x8 bh2b = *(const f16x8*)(h2l + m * HSTR + 32 + quad * 8);
        const float xtn  = xs[(m & (NBat - 1)) * XSTR + ((t + 1 < Tt) ? t + 1 : t)];
#pragma unroll
        for (int q = 0; q < 4; ++q) {
            f32x4 a2 = __builtin_amdgcn_mfma_f32_16x16x32_f16(wf2[q][0], bh1a, b2v[q], 0, 0, 0);
            a2 = __builtin_amdgcn_mfma_f32_16x16x32_f16(wf2[q][1], bh1b, a2, 0, 0, 0);
            a2 = __builtin_amdgcn_mfma_f32_16x16x32_f16(wf3[q][0], bh2a, a2, 0, 0, 0);
            a2 = __builtin_amdgcn_mfma_f32_16x16x32_f16(wf3[q][1], bh2b, a2, 0, 0, 0);
            f32x4 a1;
#pragma unroll
            for (int r = 0; r < 4; ++r) a1[r] = fmaf(xtn, wxv[q][r], b1v[q][r]);
            a1 = __builtin_amdgcn_mfma_f32_16x16x32_f16(wf1[q][0], bh1a, a1, 0, 0, 0);
            a1 = __builtin_amdgcn_mfma_f32_16x16x32_f16(wf1[q][1], bh1b, a1, 0, 0, 0);
            if (m < NBat) {   // f32x4 spans 4 consecutive units -> b128
                *(f32x4*)&pre2[(q * NBat + m) * PSTR + 16 * w + quad * 4] = a2;
                *(f32x4*)&pre1[(q * NBat + m) * PSTR + 16 * w + quad * 4] = a1;
            }
        }
        __syncthreads();                         // B2: preacts ready
    }
}

extern "C" void kernel_launch(void* const* d_in, const int* in_sizes, int n_in,
                              void* d_out, int out_size, void* d_ws, size_t ws_size,
                              hipStream_t stream)
{
    (void)in_sizes; (void)n_in; (void)out_size; (void)d_ws; (void)ws_size;
    lstm2_kernel<<<dim3(Bb / NBat), dim3(256), 0, stream>>>(
        d_in[0], d_in[1], d_in[2], d_in[3], d_in[4], d_in[5],
        d_in[6], d_in[7], d_in[8], d_in[9], d_in[10], d_out);
}

// Round 9
// 892.198 us; speedup vs baseline: 1.4430x; 1.3019x over previous
//
#include <hip/hip_runtime.h>
#include <hip/hip_bf16.h>

// LSTM2: B=1024, T=1024, H=64. R9: chain-shortening (wall = step-chain x 1024).
// 256 blocks (4 batches) x 4 waves. vs R8:
//  1. pre redistribution is INTRA-WAVE (per-wave LDS scratch, same-wave DS ops
//     are ordered) -> no barrier around it.
//  2. h1/h2 double-buffered -> WAR barrier gone. ONE barrier per step.
//  3. head reduce off critical path (partials in cell phase; finalize+store
//     overlapped with next MFMA phase on wave 0).
// Per step: Phase A (cells, 1 eval/lane/layer: batch=lane>>4, unit=16w+(lane&15))
//           -> barrier -> Phase B (24 MFMA: pre2(t)=W2.h1_t+W3.h2_{t-1},
//           pre1(t+1)=W1.h1_t+x_{t+1}; accs -> own-wave scratch).
// Layouts (m89/m91/m120): A[m=lane&15][k=(lane>>4)*8+j],
// B[k=(lane>>4)*8+j][n=lane&15], C/D: row=(lane>>4)*4+reg, col=lane&15.

typedef _Float16 f16x8 __attribute__((ext_vector_type(8)));
typedef float    f32x4 __attribute__((ext_vector_type(4)));

namespace {
constexpr int Bb = 1024;
constexpr int Tt = 1024;
constexpr int NBat = 4;    // batches per block
constexpr int HSTR = 72;   // f16 stride per batch row of h (144B, 16B-aligned)
constexpr int XSTR = 1025; // f32 stride per batch row of x
constexpr int SSTR = 20;   // f32 stride per (gate,batch) scratch row (80B, 16B-aligned)

__device__ __forceinline__ float sigm(float x) {
    float e = __builtin_amdgcn_exp2f(-1.4426950408889634f * x);
    return __builtin_amdgcn_rcpf(1.0f + e);
}
__device__ __forceinline__ float tanh_f(float x) {
    float e = __builtin_amdgcn_exp2f(-2.8853900817779268f * x);
    return __builtin_amdgcn_rcpf(1.0f + e) * 2.0f - 1.0f;
}
// Dtype sniff (proven R2-R8).
__device__ __forceinline__ bool detect_f32(const void* w) {
    const unsigned short* p = (const unsigned short*)w;
    int sane = 0;
    for (int i = 0; i < 64; ++i) {
        int e = (p[2 * i] >> 7) & 0xFF;
        if (e >= 107 && e <= 129) ++sane;
    }
    return sane < 32;
}
__device__ __forceinline__ float ld(const void* p, int i, bool f32) {
    return f32 ? ((const float*)p)[i]
               : __bfloat162float(((const __hip_bfloat16*)p)[i]);
}
__device__ __forceinline__ void st(void* p, int i, float v, bool f32) {
    if (f32) ((float*)p)[i] = v;
    else     ((__hip_bfloat16*)p)[i] = __float2bfloat16(v);
}
} // namespace

__global__ __launch_bounds__(256, 1) void lstm2_kernel(
    const void* __restrict__ x,      // [B, T]
    const void* __restrict__ w_ih1,  // [256, 1]
    const void* __restrict__ w_hh1,  // [256, 64]
    const void* __restrict__ b_ih1,  // [256]
    const void* __restrict__ b_hh1,  // [256]
    const void* __restrict__ w_ih2,  // [256, 64]
    const void* __restrict__ w_hh2,  // [256, 64]
    const void* __restrict__ b_ih2,  // [256]
    const void* __restrict__ b_hh2,  // [256]
    const void* __restrict__ w_lin,  // [1, 64]
    const void* __restrict__ b_lin,  // [1]
    void* __restrict__ out)          // [B, T]
{
    const int tid  = threadIdx.x;
    const int lane = tid & 63;
    const int w    = tid >> 6;       // wave -> unit group 16w..16w+15
    const int m    = lane & 15;      // MFMA col (batch; valid m<NBat)
    const int quad = lane >> 4;
    const int bb   = blockIdx.x * NBat;

    const bool f32 = detect_f32(w_hh1);

    __shared__ float                 xs[NBat * XSTR];
    __shared__ __align__(16) _Float16 h1buf[2][16 * HSTR];  // double-buffered
    __shared__ __align__(16) _Float16 h2buf[2][16 * HSTR];
    __shared__ __align__(16) float    scr1[4][16 * SSTR];   // per-wave pre1
    __shared__ __align__(16) float    scr2[4][16 * SSTR];   // per-wave pre2
    __shared__ float                 headl[2][16];          // [buf][w*4+b]

    // ---- stage x + zero h buffers (rows >= NBat stay 0 forever) ----
    for (int i = tid; i < NBat * 1024; i += 256)
        xs[(i >> 10) * XSTR + (i & 1023)] = ld(x, (bb + (i >> 10)) * Tt + (i & 1023), f32);
    for (int i = tid; i < 16 * HSTR; i += 256) {
        h1buf[0][i] = (_Float16)0; h1buf[1][i] = (_Float16)0;
        h2buf[0][i] = (_Float16)0; h2buf[1][i] = (_Float16)0;
    }

    // ---- one-time: A-fragments (96 VGPRs): elem j = W[64q+16w+m][32s+quad*8+j]
    f16x8 wf1[4][2], wf2[4][2], wf3[4][2];
    if (f32) {
        const float* W1 = (const float*)w_hh1;
        const float* W2 = (const float*)w_ih2;
        const float* W3 = (const float*)w_hh2;
#pragma unroll
        for (int q = 0; q < 4; ++q) {
            const int row = 64 * q + 16 * w + m;
#pragma unroll
            for (int s = 0; s < 2; ++s) {
                const int base = row * 64 + 32 * s + quad * 8;
#pragma unroll
                for (int j = 0; j < 8; ++j) {
                    wf1[q][s][j] = (_Float16)W1[base + j];
                    wf2[q][s][j] = (_Float16)W2[base + j];
                    wf3[q][s][j] = (_Float16)W3[base + j];
                }
            }
        }
    } else {
        const __hip_bfloat16* W1 = (const __hip_bfloat16*)w_hh1;
        const __hip_bfloat16* W2 = (const __hip_bfloat16*)w_ih2;
        const __hip_bfloat16* W3 = (const __hip_bfloat16*)w_hh2;
#pragma unroll
        for (int q = 0; q < 4; ++q) {
            const int row = 64 * q + 16 * w + m;
#pragma unroll
            for (int s = 0; s < 2; ++s) {
                const int base = row * 64 + 32 * s + quad * 8;
#pragma unroll
                for (int j = 0; j < 8; ++j) {
                    wf1[q][s][j] = (_Float16)__bfloat162float(W1[base + j]);
                    wf2[q][s][j] = (_Float16)__bfloat162float(W2[base + j]);
                    wf3[q][s][j] = (_Float16)__bfloat162float(W3[base + j]);
                }
            }
        }
    }
    f32x4 b1v[4], b2v[4], wxv[4];
#pragma unroll
    for (int q = 0; q < 4; ++q)
#pragma unroll
        for (int r = 0; r < 4; ++r) {
            const int row = 64 * q + 16 * w + quad * 4 + r;
            b1v[q][r] = ld(b_ih1, row, f32) + ld(b_hh1, row, f32);
            b2v[q][r] = ld(b_ih2, row, f32) + ld(b_hh2, row, f32);
            wxv[q][r] = ld(w_ih1, row, f32);
        }
    // cell mapping: lane -> (batch cb, unit 16w+uo)
    const int cb = lane >> 4;
    const int uo = lane & 15;
    const float wl_u = ld(w_lin, 16 * w + uo, f32);
    const float blin = ld(b_lin, 0, f32);
    float c1 = 0.0f, c2 = 0.0f;
    __syncthreads();   // xs + zeroed h bufs visible

    // ---- prologue: pre1(0) = x_0*wx + b1 into own-wave scr1 ----
    if (m < NBat) {
        const float x0 = xs[m * XSTR];
#pragma unroll
        for (int q = 0; q < 4; ++q) {
            f32x4 v;
#pragma unroll
            for (int r = 0; r < 4; ++r) v[r] = fmaf(x0, wxv[q][r], b1v[q][r]);
            *(f32x4*)&scr1[w][(q * 4 + m) * SSTR + quad * 4] = v;
        }
    }
    // no barrier: A(0) reads own-wave scratch only

    for (int t = 0; t < Tt; ++t) {
        const int cur = t & 1;
        // ---- Phase A: cells (own-wave scratch; 1 eval/lane/layer) ----
        {
            float gi = scr1[w][(0 * 4 + cb) * SSTR + uo];
            float gf = scr1[w][(1 * 4 + cb) * SSTR + uo];
            float gz = scr1[w][(2 * 4 + cb) * SSTR + uo];
            float go = scr1[w][(3 * 4 + cb) * SSTR + uo];
            float ig = sigm(gi), fg = sigm(gf), gg = tanh_f(gz), og = sigm(go);
            c1 = fmaf(fg, c1, ig * gg);
            h1buf[cur][cb * HSTR + 16 * w + uo] = (_Float16)(og * tanh_f(c1));
        }
        if (t > 0) {
            float gi = scr2[w][(0 * 4 + cb) * SSTR + uo];
            float gf = scr2[w][(1 * 4 + cb) * SSTR + uo];
            float gz = scr2[w][(2 * 4 + cb) * SSTR + uo];
            float go = scr2[w][(3 * 4 + cb) * SSTR + uo];
            float ig = sigm(gi), fg = sigm(gf), gg = tanh_f(gz), og = sigm(go);
            c2 = fmaf(fg, c2, ig * gg);
            float h = og * tanh_f(c2);
            h2buf[cur][cb * HSTR + 16 * w + uo] = (_Float16)h;
            float p = h * wl_u;               // partial over this wave's units
            p += __shfl_xor(p, 1); p += __shfl_xor(p, 2);
            p += __shfl_xor(p, 4); p += __shfl_xor(p, 8);
            if (uo == 0) headl[cur][w * 4 + cb] = p;
        }
        __syncthreads();                      // THE barrier: h_t / partials visible

        // ---- Phase B: MFMA + head finalize (overlapped) ----
        if (t > 0 && tid < NBat) {            // wave 0: finalize out[t-1]
            float s = blin;
#pragma unroll
            for (int k = 0; k < 4; ++k) s += headl[cur][k * 4 + tid];
            st(out, (bb + tid) * Tt + (t - 1), s, f32);
        }
        const f16x8 bh1a = *(const f16x8*)(h1buf[cur] + m * HSTR + quad * 8);
        const f16x8 bh1b = *(const f16x8*)(h1buf[cur] + m * HSTR + 32 + quad * 8);
        const f16x8 bh2a = *(const f16x8*)(h2buf[cur] + m * HSTR + quad * 8);
        const f16x8 bh2b = *(const f16x8*)(h2buf[cur] + m * HSTR + 32 + quad * 8);
        const float xtn  = xs[(m & (NBat - 1)) * XSTR + ((t + 1 < Tt) ? t + 1 : t)];
#pragma unroll
        for (int q = 0; q < 4; ++q) {
            f32x4 a2 = __builtin_amdgcn_mfma_f32_16x16x32_f16(wf2[q][0], bh1a, b2v[q], 0, 0, 0);
            a2 = __builtin_amdgcn_mfma_f32_16x16x32_f16(wf2[q][1], bh1b, a2, 0, 0, 0);
            a2 = __builtin_amdgcn_mfma_f32_16x16x32_f16(wf3[q][0], bh2a, a2, 0, 0, 0);
            a2 = __builtin_amdgcn_mfma_f32_16x16x32_f16(wf3[q][1], bh2b, a2, 0, 0, 0);
            f32x4 a1;
#pragma unroll
            for (int r = 0; r < 4; ++r) a1[r] = fmaf(xtn, wxv[q][r], b1v[q][r]);
            a1 = __builtin_amdgcn_mfma_f32_16x16x32_f16(wf1[q][0], bh1a, a1, 0, 0, 0);
            a1 = __builtin_amdgcn_mfma_f32_16x16x32_f16(wf1[q][1], bh1b, a1, 0, 0, 0);
            if (m < NBat) {                   // own-wave scratch, in-order DS
                *(f32x4*)&scr2[w][(q * 4 + m) * SSTR + quad * 4] = a2;
                *(f32x4*)&scr1[w][(q * 4 + m) * SSTR + quad * 4] = a1;
            }
        }
        // no second barrier: h bufs double-buffered; scratch is per-wave
    }

    // ---- epilogue: cell2(T-1) + head + out[T-1] ----
    {
        float gi = scr2[w][(0 * 4 + cb) * SSTR + uo];
        float gf = scr2[w][(1 * 4 + cb) * SSTR + uo];
        float gz = scr2[w][(2 * 4 + cb) * SSTR + uo];
        float go = scr2[w][(3 * 4 + cb) * SSTR + uo];
        float ig = sigm(gi), fg = sigm(gf), gg = tanh_f(gz), og = sigm(go);
        c2 = fmaf(fg, c2, ig * gg);
        float h = og * tanh_f(c2);
        float p = h * wl_u;
        p += __shfl_xor(p, 1); p += __shfl_xor(p, 2);
        p += __shfl_xor(p, 4); p += __shfl_xor(p, 8);
        if (uo == 0) headl[0][w * 4 + cb] = p;
    }
    __syncthreads();
    if (tid < NBat) {
        float s = blin;
#pragma unroll
        for (int k = 0; k < 4; ++k) s += headl[0][k * 4 + tid];
        st(out, (bb + tid) * Tt + (Tt - 1), s, f32);
    }
}

extern "C" void kernel_launch(void* const* d_in, const int* in_sizes, int n_in,
                              void* d_out, int out_size, void* d_ws, size_t ws_size,
                              hipStream_t stream)
{
    (void)in_sizes; (void)n_in; (void)out_size; (void)d_ws; (void)ws_size;
    lstm2_kernel<<<dim3(Bb / NBat), dim3(256), 0, stream>>>(
        d_in[0], d_in[1], d_in[2], d_in[3], d_in[4], d_in[5],
        d_in[6], d_in[7], d_in[8], d_in[9], d_in[10], d_out);
}